// Round 8
// baseline (697.686 us; speedup 1.0000x reference)
//
#include <hip/hip_runtime.h>
#include <stdint.h>

typedef unsigned long long u64;

#define B_ 4
#define N_ 49104
#define C_ 90
#define NCLS (B_ * C_)        // 360
#define MAXK 100
#define THR 0.01f
#define CHK 512               // greedy window / chunk size (matches 8 x 64-lane register sets)
#define NBIN 2304             // fine bins over scores in (0.9296875, 1.0); lambda ~ 1.5
#define BINBASE 0x3F6E0000u   // float bits 0.9296875 (valid for all t0 tiers >= 0.93)
#define BINSH 9
#define ACH 128               // anchors per select block
#define NCH ((N_ + ACH - 1) / ACH)   // 384
#define CAPC 32               // per-(class, select-block) LDS capacity; mean 8.96, +8 sigma

// ---------- exact fp32 math matching the numpy/jax reference ----------
__device__ __forceinline__ float area_of(float y1, float x1, float y2, float x2) {
#pragma clang fp contract(off)
  return (y2 - y1) * (x2 - x1);
}

// aa = SELECTED (kept) box area, ba = candidate area (reference arg order)
__device__ __forceinline__ bool iou_gt(float ay1, float ax1, float ay2, float ax2, float aa,
                                       float by1, float bx1, float by2, float bx2, float ba) {
#pragma clang fp contract(off)
  float y1 = fmaxf(ay1, by1);
  float x1 = fmaxf(ax1, bx1);
  float y2 = fminf(ay2, by2);
  float x2 = fminf(ax2, bx2);
  float inter = fmaxf(y2 - y1, 0.0f) * fmaxf(x2 - x1, 0.0f);
  float denom = aa + ba - inter + 1e-8f;
  return (inter / denom) > 0.1f;
}

__device__ __forceinline__ u64 umax64(u64 a, u64 b) { return a > b ? a : b; }

__device__ __forceinline__ u64 shfl_xor_u64(u64 v, int m) {
  int lo = __shfl_xor((int)(unsigned)v, m);
  int hi = __shfl_xor((int)(unsigned)(v >> 32), m);
  return ((u64)(unsigned)hi << 32) | (u64)(unsigned)lo;
}

__device__ __forceinline__ int key2bin(u64 k) {
  int d = (int)((unsigned)(k >> 32) - BINBASE);
  int bin = d >> BINSH;
  if (d < 0) bin = 0;
  if (bin > NBIN - 1) bin = NBIN - 1;
  return bin;
}

// ---------- kernel S: 4-batched streaming read -> per-class LDS bins -> bulk flush ----------
__global__ __launch_bounds__(256) void select_kernel(const float* __restrict__ cls,
                                                     u64* __restrict__ keybuf,
                                                     unsigned* __restrict__ cnt,
                                                     int capsel, float t0) {
  __shared__ u64 ll[C_ * CAPC];        // 23040 B
  __shared__ unsigned lcnt[C_];
  __shared__ unsigned base_s[C_];
  int blk = blockIdx.x;
  int b = blk / NCH, ch = blk - b * NCH;
  int a0 = ch * ACH;
  int aEnd = a0 + ACH; if (aEnd > N_) aEnd = N_;
  int e0 = a0 * C_;                    // byte offset a0*360: 16B-aligned
  int nelem = (aEnd - a0) * C_;
  int tid = threadIdx.x;

  for (int i = tid; i < C_; i += 256) lcnt[i] = 0u;
  __syncthreads();

  const float4* src4 = (const float4*)(cls + (size_t)b * N_ * C_ + e0);
  int n4 = nelem >> 2;
  auto proc = [&](float s, int e) {
    if (s > t0) {
      unsigned n = (unsigned)e / (unsigned)C_;
      unsigned c = (unsigned)e - n * (unsigned)C_;
      u64 key = ((u64)__float_as_uint(s) << 32) | (u64)(0xFFFFFFFFu - n);
      unsigned pos = atomicAdd(&lcnt[c], 1u);
      if (pos < CAPC) {
        ll[c * CAPC + pos] = key;
      } else {                         // LDS overflow (p ~ 1e-13): exact global spill
        unsigned g = (unsigned)(b * C_) + c;
        unsigned gp = atomicAdd(&cnt[g * 16], 1u);
        if (gp < (unsigned)capsel) keybuf[(size_t)g * capsel + gp] = key;
      }
    }
  };
  // 4 independent loads in flight before any atomic/branch processing
  for (int i4 = tid; i4 < n4; i4 += 1024) {
    float4 v0, v1, v2, v3;
    int g1 = i4 + 256, g2 = i4 + 512, g3 = i4 + 768;
    v0 = src4[i4];
    if (g1 < n4) v1 = src4[g1];
    if (g2 < n4) v2 = src4[g2];
    if (g3 < n4) v3 = src4[g3];
#pragma unroll
    for (int j = 0; j < 4; ++j) proc((&v0.x)[j], e0 + i4 * 4 + j);
    if (g1 < n4) {
#pragma unroll
      for (int j = 0; j < 4; ++j) proc((&v1.x)[j], e0 + g1 * 4 + j);
    }
    if (g2 < n4) {
#pragma unroll
      for (int j = 0; j < 4; ++j) proc((&v2.x)[j], e0 + g2 * 4 + j);
    }
    if (g3 < n4) {
#pragma unroll
      for (int j = 0; j < 4; ++j) proc((&v3.x)[j], e0 + g3 * 4 + j);
    }
  }
  __syncthreads();

  if (tid < C_) {
    unsigned cc = lcnt[tid]; if (cc > CAPC) cc = CAPC;
    base_s[tid] = atomicAdd(&cnt[(b * C_ + tid) * 16], cc);
  }
  __syncthreads();

  for (int i = tid; i < C_ * CAPC; i += 256) {
    int c = i >> 5, j = i & 31;
    unsigned cc = lcnt[c]; if (cc > CAPC) cc = CAPC;
    if ((unsigned)j < cc) {
      unsigned pos = base_s[c] + (unsigned)j;
      if (pos < (unsigned)capsel)
        keybuf[(size_t)(b * C_ + c) * capsel + pos] = ll[i];
    }
  }
}

// ---------- kernel A: LDS keys + rank-scatter sort (512 window) + eager bitmask greedy ----------
__global__ __launch_bounds__(256) void nms_kernel(const float* __restrict__ boxes,
                                                  const float* __restrict__ cls,
                                                  const u64* __restrict__ keybuf,
                                                  const unsigned* __restrict__ cnt,
                                                  int capsel, float t0,
                                                  u64* __restrict__ keepkeys,
                                                  int* __restrict__ nk_arr) {
  int gcls = blockIdx.x;
  int b = gcls / C_, c = gcls - b * C_;
  __shared__ u64 karr[4096];           // 32 KB raw keys (loaded once)
  __shared__ unsigned hist[NBIN];      //  9 KB
  __shared__ unsigned rb[NBIN];        //  9 KB rank base / scatter cursor
  __shared__ u64 ck[CHK];              //  4 KB sorted window
  __shared__ float4 ckbox[CHK];        //  8 KB candidate boxes
  __shared__ float carea[CHK];         //  2 KB candidate areas
  __shared__ float4 kb[MAXK];          // kept boxes
  __shared__ float ka[MAXK];           // kept areas
  __shared__ u64 red[256];             //  2 KB fallback reduction
  __shared__ unsigned wsum[4];
  __shared__ int sh_blo, sh_run, sh_nk, sh_over;
  int tid = threadIdx.x;
  int lane = tid & 63;
  int wid = tid >> 6;

  for (int i = tid; i < MAXK; i += 256) keepkeys[(size_t)gcls * MAXK + i] = 0ull;
  for (int i = tid; i < NBIN; i += 256) hist[i] = 0u;
  if (tid == 0) { sh_nk = 0; sh_over = 0; }
  __syncthreads();

  unsigned Mraw = cnt[gcls * 16];
  bool overflow = (Mraw > (unsigned)capsel);   // p < 1e-25: full brute force below
  int M = overflow ? 0 : (int)Mraw;

  const u64* src = keybuf + (size_t)gcls * capsel;
  for (int i = tid; i < M; i += 256) {
    u64 k = src[i];
    karr[i] = k;
    atomicAdd(&hist[key2bin(k)], 1u);
  }
  __syncthreads();

  const float4* bx4 = (const float4*)(boxes + (size_t)b * N_ * 4);
  int nk = 0;                          // authoritative in wave 0
  int bhi = NBIN, ext = 0;
  const int W = 9;                     // NBIN / 256

  while (ext < M && sh_nk < MAXK) {
    if (tid == 0) sh_blo = bhi;
    __syncthreads();

    // suffix ranks over reversed stripes: rb[bin] = #keys in bins (bin, bhi)
    int j0 = tid * W;
    unsigned psum = 0;
#pragma unroll
    for (int q = 0; q < W; ++q) {
      int bin = bhi - 1 - (j0 + q);
      if (bin >= 0) psum += hist[bin];
    }
    unsigned incl = psum;
#pragma unroll
    for (int s = 1; s < 64; s <<= 1) {
      unsigned v = (unsigned)__shfl_up((int)incl, s);
      if (lane >= s) incl += v;
    }
    if (lane == 63) wsum[wid] = incl;
    __syncthreads();
    unsigned base = 0;
    for (int w2 = 0; w2 < wid; ++w2) base += wsum[w2];
    unsigned running = base + incl - psum;
    int myblo = bhi;
#pragma unroll
    for (int q = 0; q < W; ++q) {
      int bin = bhi - 1 - (j0 + q);
      if (bin >= 0) {
        rb[bin] = running;
        running += hist[bin];
        if (running <= CHK) myblo = bin;   // inclusive suffix <= CHK qualifies
      }
    }
    if (myblo < bhi) atomicMin(&sh_blo, myblo);
    __syncthreads();
    if (tid == 0) {
      int blo = sh_blo;
      int run = (blo < bhi) ? (int)(rb[blo] + hist[blo]) : 0;
      if (run == 0) sh_over = 1;       // single bin > CHK keys (never for uniform scores)
      sh_run = run;
    }
    __syncthreads();
    if (sh_over) break;
    int blo = sh_blo, run = sh_run;

    // scatter window keys into exact rank positions
    for (int i = tid; i < M; i += 256) {
      u64 k = karr[i];
      int bin = key2bin(k);
      if (bin >= blo && bin < bhi) {
        unsigned pos = atomicAdd(&rb[bin], 1u);
        ck[pos] = k;
      }
    }
    __syncthreads();
    // intra-bin fixup: insertion-sort each bin run descending by full key (exact ties)
    int wlen = bhi - blo;
    for (int idx = tid; idx < wlen; idx += 256) {
      int bin = blo + idx;
      unsigned h2 = hist[bin];
      if (h2 >= 2u) {
        unsigned end = rb[bin];        // start + h2 after scatter
        unsigned st = end - h2;
        for (unsigned a = st + 1; a < end; ++a) {
          u64 kv = ck[a]; unsigned p2 = a;
          while (p2 > st && ck[p2 - 1] < kv) { ck[p2] = ck[p2 - 1]; --p2; }
          ck[p2] = kv;
        }
      }
    }
    __syncthreads();
    // stage candidate boxes + areas
    for (int i = tid; i < run; i += 256) {
      float4 v = bx4[0xFFFFFFFFu - (unsigned)(ck[i] & 0xFFFFFFFFull)];
      ckbox[i] = v;
      carea[i] = area_of(v.x, v.y, v.z, v.w);
    }
    __syncthreads();

    // eager-bitmask greedy on wave 0 (r5-validated): pop lowest alive bit == next keep;
    // per keep suppress only sets >= current word (lower bits already zero).
    if (wid == 0) {
      float4 cb_[8]; float ca_[8];
      u64 alive[8];
#pragma unroll
      for (int s = 0; s < 8; ++s) {
        int idx = s * 64 + lane;
        if (idx < run) { cb_[s] = ckbox[idx]; ca_[s] = carea[idx]; }
        else { cb_[s] = make_float4(-1e30f, -1e30f, -1e30f, -1e30f); ca_[s] = 0.f; }
        int lo = s * 64;
        alive[s] = (run >= lo + 64) ? ~0ull
                 : (run > lo ? ((1ull << (run - lo)) - 1ull) : 0ull);
      }
      // catch-up vs keeps from previous chunks (chunk >= 2 only)
      for (int j = 0; j < nk; ++j) {
        float4 sb = kb[j]; float sa = ka[j];
#pragma unroll
        for (int s = 0; s < 8; ++s)
          alive[s] &= ~__ballot(iou_gt(sb.x, sb.y, sb.z, sb.w, sa,
                                       cb_[s].x, cb_[s].y, cb_[s].z, cb_[s].w, ca_[s]));
      }
      int w = 0;
      while (nk < MAXK) {
        while (w < 8 && alive[w] == 0ull) ++w;   // w is wave-uniform
        if (w == 8) break;
        int bit = __ffsll((long long)alive[w]) - 1;
        int ii = (w << 6) + bit;
        float4 sb = ckbox[ii];          // wave-uniform broadcast
        float sa = carea[ii];
        u64 key = ck[ii];
        if (lane == 0) {
          unsigned anchor = 0xFFFFFFFFu - (unsigned)(key & 0xFFFFFFFFull);
          unsigned flat = anchor * C_ + (unsigned)c;
          keepkeys[(size_t)gcls * MAXK + nk] =
              (key & 0xFFFFFFFF00000000ull) | (u64)(0xFFFFFFFFu - flat);
          kb[nk] = sb; ka[nk] = sa;
        }
        ++nk;
        // self-bit clears via self-IOU ~ 1 > 0.1
#pragma unroll
        for (int s = 0; s < 8; ++s) {
          if (s >= w) {
            alive[s] &= ~__ballot(iou_gt(sb.x, sb.y, sb.z, sb.w, sa,
                                         cb_[s].x, cb_[s].y, cb_[s].z, cb_[s].w, ca_[s]));
          }
        }
      }
      if (lane == 0) sh_nk = nk;
    }
    __syncthreads();
    ext += run;
    bhi = blo;
  }

  // ---- inline exact continuation (cold path) ----
  int nkF = sh_nk;
  if (nkF < MAXK) {
    float teff;
    if (overflow)     teff = 2.0f;
    else if (sh_over) teff = __uint_as_float(BINBASE + ((unsigned)bhi << BINSH) - 1u);
    else              teff = t0;
    const float* sbase = cls + (size_t)b * N_ * C_ + c;
    const float* bx = boxes + (size_t)b * N_ * 4;
    u64* kkp = keepkeys + (size_t)gcls * MAXK;
    int nk2 = nkF;
    while (nk2 < MAXK) {
      u64 best = 0ull;
      for (int n = tid; n < N_; n += 256) {
        float s = sbase[(size_t)n * C_];
        if (s > THR && s <= teff) {
          float y1 = bx[(size_t)n * 4 + 0], x1 = bx[(size_t)n * 4 + 1];
          float y2 = bx[(size_t)n * 4 + 2], x2 = bx[(size_t)n * 4 + 3];
          float ar = area_of(y1, x1, y2, x2);
          bool ov = false;
          for (int j = 0; j < nk2; ++j) {
            float4 kbj = kb[j];
            if (iou_gt(kbj.x, kbj.y, kbj.z, kbj.w, ka[j], y1, x1, y2, x2, ar)) { ov = true; break; }
          }
          if (!ov) {
            u64 key = ((u64)__float_as_uint(s) << 32) | (u64)(0xFFFFFFFFu - (unsigned)n);
            best = umax64(best, key);
          }
        }
      }
      red[tid] = best;
      __syncthreads();
      for (int sft = 128; sft > 0; sft >>= 1) {
        if (tid < sft) red[tid] = umax64(red[tid], red[tid + sft]);
        __syncthreads();
      }
      u64 sel = red[0];
      __syncthreads();
      if (sel == 0ull) {
        if (tid == 0) {  // exhausted before MAXK: reference quirk -> keep[anchor 0] = False
          unsigned target = 0xFFFFFFFFu - (unsigned)c;  // anchor 0 -> flat == c
          for (int j = 0; j < nk2; ++j)
            if ((unsigned)(kkp[j] & 0xFFFFFFFFull) == target) kkp[j] = 0ull;
        }
        break;
      }
      unsigned anchor = 0xFFFFFFFFu - (unsigned)(sel & 0xFFFFFFFFull);
      if (tid == 0) {
        float y1 = bx[(size_t)anchor * 4 + 0], x1 = bx[(size_t)anchor * 4 + 1];
        float y2 = bx[(size_t)anchor * 4 + 2], x2 = bx[(size_t)anchor * 4 + 3];
        kb[nk2] = make_float4(y1, x1, y2, x2);
        ka[nk2] = area_of(y1, x1, y2, x2);
        unsigned flat = anchor * C_ + (unsigned)c;
        kkp[nk2] = (sel & 0xFFFFFFFF00000000ull) | (u64)(0xFFFFFFFFu - flat);
      }
      ++nk2;
      __syncthreads();
    }
    nkF = nk2;
  }
  if (tid == 0) nk_arr[gcls] = nkF;
}

// ---------- kernel C: rank-scatter top-100 (exact; serial fallback for tie floods) ----------
__global__ __launch_bounds__(256) void merge_kernel(const float* __restrict__ boxes,
                                                    const u64* __restrict__ keepkeys,
                                                    const int* __restrict__ nk_arr,
                                                    float* __restrict__ out) {
  int b = blockIdx.x;
  int tid = threadIdx.x;
  int lane = tid & 63;
  int wid = tid >> 6;
  __shared__ unsigned hist[NBIN];
  __shared__ unsigned rb[NBIN];
  __shared__ unsigned wsum[4];
  __shared__ u64 mk[512];
  __shared__ u64 selk[MAXK];
  __shared__ int sh_thr;
  const u64* kk = keepkeys + (size_t)b * C_ * MAXK;
  const int TOT = C_ * MAXK;           // 9000

  for (int i = tid; i < NBIN; i += 256) hist[i] = 0u;
  for (int i = tid; i < 512; i += 256) mk[i] = 0ull;
  if (tid == 0) sh_thr = -1;
  __syncthreads();
  for (int i = tid; i < TOT; i += 256) {
    u64 k = kk[i];
    if (k != 0ull) atomicAdd(&hist[key2bin(k)], 1u);
  }
  __syncthreads();

  // suffix scan: rb[bin] = #keys in bins > bin; thr = largest bin with rb+hist >= MAXK
  const int W = 9;
  int j0 = tid * W;
  unsigned psum = 0;
#pragma unroll
  for (int q = 0; q < W; ++q) {
    int bin = NBIN - 1 - (j0 + q);
    if (bin >= 0) psum += hist[bin];
  }
  unsigned incl = psum;
#pragma unroll
  for (int s = 1; s < 64; s <<= 1) {
    unsigned v = (unsigned)__shfl_up((int)incl, s);
    if (lane >= s) incl += v;
  }
  if (lane == 63) wsum[wid] = incl;
  __syncthreads();
  unsigned base = 0;
  for (int w2 = 0; w2 < wid; ++w2) base += wsum[w2];
  unsigned running = base + incl - psum;
  int mythr = -1;
#pragma unroll
  for (int q = 0; q < W; ++q) {
    int bin = NBIN - 1 - (j0 + q);
    if (bin >= 0) {
      rb[bin] = running;
      running += hist[bin];
      if (mythr < 0 && running >= (unsigned)MAXK) mythr = bin;
    }
  }
  if (mythr >= 0) atomicMax(&sh_thr, mythr);
  __syncthreads();

  int thr = sh_thr; if (thr < 0) thr = 0;
  unsigned S = rb[thr] + hist[thr];    // total candidates at/above threshold bin

  if (S <= 512u) {
    // rank-scatter + intra-bin insertion fixup (exact full-key descending order)
    for (int i = tid; i < TOT; i += 256) {
      u64 k = kk[i];
      if (k != 0ull) {
        int bin = key2bin(k);
        if (bin >= thr) {
          unsigned pos = atomicAdd(&rb[bin], 1u);
          mk[pos] = k;
        }
      }
    }
    __syncthreads();
    for (int bin = thr + tid; bin < NBIN; bin += 256) {
      unsigned h2 = hist[bin];
      if (h2 >= 2u) {
        unsigned end = rb[bin];
        unsigned st = end - h2;
        for (unsigned a = st + 1; a < end; ++a) {
          u64 kv = mk[a]; unsigned p2 = a;
          while (p2 > st && mk[p2 - 1] < kv) { mk[p2] = mk[p2 - 1]; --p2; }
          mk[p2] = kv;
        }
      }
    }
    __syncthreads();
    for (int r = tid; r < MAXK; r += 256) selk[r] = mk[r];
    __syncthreads();
  } else {
    // degenerate tie flood: exact serial tournament on wave 0
    if (wid == 0) {
      int c0 = lane, c1 = lane + 64;
      int len0 = (c0 < C_) ? nk_arr[b * C_ + c0] : 0;
      int len1 = (c1 < C_) ? nk_arr[b * C_ + c1] : 0;
      int h0 = 0, h1 = 0;
      auto fetchc = [&](int cc, int& h, int len) -> u64 {
        while (h < len) {
          u64 k = kk[(size_t)cc * MAXK + h];
          if (k != 0ull) return k;
          ++h;
        }
        return 0ull;
      };
      u64 cand0 = (c0 < C_) ? fetchc(c0, h0, len0) : 0ull;
      u64 cand1 = (c1 < C_) ? fetchc(c1, h1, len1) : 0ull;
      for (int r = 0; r < MAXK; ++r) {
        u64 my = umax64(cand0, cand1);
        u64 g = my;
#pragma unroll
        for (int m = 1; m < 64; m <<= 1) g = umax64(g, shfl_xor_u64(g, m));
        if (lane == 0) selk[r] = g;
        if (g != 0ull && my == g) {
          if (cand0 == g) { ++h0; cand0 = fetchc(c0, h0, len0); }
          else            { ++h1; cand1 = fetchc(c1, h1, len1); }
        }
      }
    }
    __syncthreads();
  }

  for (int r = tid; r < MAXK; r += 256) {
    u64 s = selk[r];
    float oy1, ox1, oy2, ox2, sc, lb;
    if (s != 0ull) {
      unsigned flat = 0xFFFFFFFFu - (unsigned)(s & 0xFFFFFFFFull);
      unsigned anchor = flat / C_;
      unsigned label = flat - anchor * C_;
      sc = __uint_as_float((unsigned)(s >> 32));
      const float4 bp = ((const float4*)(boxes + (size_t)b * N_ * 4))[anchor];
      oy1 = bp.x; ox1 = bp.y; oy2 = bp.z; ox2 = bp.w;
      lb = (float)label;
    } else {
      oy1 = ox1 = oy2 = ox2 = -1.0f; sc = -1.0f; lb = -1.0f;
    }
    float* bo = out + ((size_t)b * MAXK + r) * 4;
    bo[0] = oy1; bo[1] = ox1; bo[2] = oy2; bo[3] = ox2;
    out[(size_t)B_ * MAXK * 4 + b * MAXK + r] = sc;
    out[(size_t)B_ * MAXK * 4 + B_ * MAXK + b * MAXK + r] = lb;
  }
}

extern "C" void kernel_launch(void* const* d_in, const int* in_sizes, int n_in,
                              void* d_out, int out_size, void* d_ws, size_t ws_size,
                              hipStream_t stream) {
  const float* boxes = (const float*)d_in[0];   // [B,N,4]
  const float* cls = (const float*)d_in[1];     // [B,N,C]
  char* ws = (char*)d_ws;

  // capacity/threshold tiers by available workspace (all t0 >= 0.93 for BINBASE validity)
  int capsel; float t0;
  auto need_for = [](int cap) -> size_t {
    return 23040 + (size_t)NCLS * cap * 8 + 288000 + 1440;
  };
  if (ws_size >= need_for(4096))      { capsel = 4096; t0 = 0.93f;  }  // M ~ 3437 +/- 57
  else if (ws_size >= need_for(2048)) { capsel = 2048; t0 = 0.962f; }  // M ~ 1866 +/- 42
  else                                { capsel = 1024; t0 = 0.985f; }  // M ~  737 +/- 27

  unsigned* cnt = (unsigned*)ws;                      // 360 counters, 64B padded
  u64* keybuf = (u64*)(ws + 23040);
  size_t off = 23040 + (size_t)NCLS * capsel * 8;
  u64* keepkeys = (u64*)(ws + off);      off += 288000;
  int* nk_arr = (int*)(ws + off);

  hipMemsetAsync(cnt, 0, 23040, stream);
  select_kernel<<<B_ * NCH, 256, 0, stream>>>(cls, keybuf, cnt, capsel, t0);
  nms_kernel<<<NCLS, 256, 0, stream>>>(boxes, cls, keybuf, cnt, capsel, t0,
                                       keepkeys, nk_arr);
  merge_kernel<<<B_, 256, 0, stream>>>(boxes, keepkeys, nk_arr, (float*)d_out);
}

// Round 9
// 211.871 us; speedup vs baseline: 3.2930x; 3.2930x over previous
//
#include <hip/hip_runtime.h>
#include <stdint.h>

typedef unsigned long long u64;

#define B_ 4
#define N_ 49104
#define C_ 90
#define NCLS (B_ * C_)        // 360
#define MAXK 100
#define THR 0.01f
#define CHK 512               // chunk sort size (r5 nms)
#define NB2 2048              // r5 nms fine histogram bins (score_bits[22:12])
#define ACH 128               // anchors per select block (r7)
#define NCH ((N_ + ACH - 1) / ACH)   // 384
#define CAPC 32               // per-(class, select-block) LDS capacity; mean 8.96, +8 sigma
#define NBIN_M 1280           // merge bins (r7)
#define BINBASE 0x3F6E0000u   // float bits 0.9296875 (valid for all t0 tiers >= 0.93)
#define BINSH_M 10

// ---------- exact fp32 math matching the numpy/jax reference ----------
__device__ __forceinline__ float area_of(float y1, float x1, float y2, float x2) {
#pragma clang fp contract(off)
  return (y2 - y1) * (x2 - x1);
}

// aa = SELECTED (kept) box area, ba = candidate area (reference arg order)
__device__ __forceinline__ bool iou_gt(float ay1, float ax1, float ay2, float ax2, float aa,
                                       float by1, float bx1, float by2, float bx2, float ba) {
#pragma clang fp contract(off)
  float y1 = fmaxf(ay1, by1);
  float x1 = fmaxf(ax1, bx1);
  float y2 = fminf(ay2, by2);
  float x2 = fminf(ax2, bx2);
  float inter = fmaxf(y2 - y1, 0.0f) * fmaxf(x2 - x1, 0.0f);
  float denom = aa + ba - inter + 1e-8f;
  return (inter / denom) > 0.1f;
}

__device__ __forceinline__ u64 umax64(u64 a, u64 b) { return a > b ? a : b; }

__device__ __forceinline__ u64 shfl_xor_u64(u64 v, int m) {
  int lo = __shfl_xor((int)(unsigned)v, m);
  int hi = __shfl_xor((int)(unsigned)(v >> 32), m);
  return ((u64)(unsigned)hi << 32) | (u64)(unsigned)lo;
}

__device__ __forceinline__ int key2bin_m(u64 k) {
  int d = (int)((unsigned)(k >> 32) - BINBASE);
  int bin = d >> BINSH_M;
  if (d < 0) bin = 0;
  if (bin > NBIN_M - 1) bin = NBIN_M - 1;
  return bin;
}

// ---------- kernel S (r7-verbatim): slab read -> per-class LDS bins -> bulk flush ----------
__global__ __launch_bounds__(256) void select_kernel(const float* __restrict__ cls,
                                                     u64* __restrict__ keybuf,
                                                     unsigned* __restrict__ cnt,
                                                     int capsel, float t0) {
  __shared__ u64 ll[C_ * CAPC];        // 23040 B
  __shared__ unsigned lcnt[C_];
  __shared__ unsigned base_s[C_];
  int blk = blockIdx.x;
  int b = blk / NCH, ch = blk - b * NCH;
  int a0 = ch * ACH;
  int aEnd = a0 + ACH; if (aEnd > N_) aEnd = N_;
  int e0 = a0 * C_;                    // byte offset a0*360: 16B-aligned
  int nelem = (aEnd - a0) * C_;
  int tid = threadIdx.x;

  for (int i = tid; i < C_; i += 256) lcnt[i] = 0u;
  __syncthreads();

  const float4* src4 = (const float4*)(cls + (size_t)b * N_ * C_ + e0);
  int n4 = nelem >> 2;
  for (int i4 = tid; i4 < n4; i4 += 256) {
    float4 v = src4[i4];
#pragma unroll
    for (int j = 0; j < 4; ++j) {
      float s = (&v.x)[j];
      if (s > t0) {
        int e = e0 + i4 * 4 + j;
        unsigned n = (unsigned)e / (unsigned)C_;
        unsigned c = (unsigned)e - n * (unsigned)C_;
        u64 key = ((u64)__float_as_uint(s) << 32) | (u64)(0xFFFFFFFFu - n);
        unsigned pos = atomicAdd(&lcnt[c], 1u);
        if (pos < CAPC) {
          ll[c * CAPC + pos] = key;
        } else {                       // LDS overflow (p ~ 1e-13): exact global spill
          unsigned g = (unsigned)(b * C_) + c;
          unsigned gp = atomicAdd(&cnt[g * 16], 1u);
          if (gp < (unsigned)capsel) keybuf[(size_t)g * capsel + gp] = key;
        }
      }
    }
  }
  __syncthreads();

  if (tid < C_) {
    unsigned cc = lcnt[tid]; if (cc > CAPC) cc = CAPC;
    base_s[tid] = atomicAdd(&cnt[(b * C_ + tid) * 16], cc);
  }
  __syncthreads();

  for (int i = tid; i < C_ * CAPC; i += 256) {
    int c = i >> 5, j = i & 31;
    unsigned cc = lcnt[c]; if (cc > CAPC) cc = CAPC;
    if ((unsigned)j < cc) {
      unsigned pos = base_s[c] + (unsigned)j;
      if (pos < (unsigned)capsel)
        keybuf[(size_t)(b * C_ + c) * capsel + pos] = ll[i];
    }
  }
}

// ---------- kernel A (r5-verbatim): LDS keys + chunked bitonic + eager bitmask greedy ----------
__global__ __launch_bounds__(256) void nms_kernel(const float* __restrict__ boxes,
                                                  const float* __restrict__ cls,
                                                  const u64* __restrict__ keybuf,
                                                  const unsigned* __restrict__ cnt,
                                                  int capsel, float t0,
                                                  u64* __restrict__ keepkeys,
                                                  int* __restrict__ nk_arr) {
  int gcls = blockIdx.x;
  int b = gcls / C_, c = gcls - b * C_;
  __shared__ u64 karr[4096];           // 32 KB raw keys
  __shared__ unsigned hist[NB2];       //  8 KB
  __shared__ u64 ck[CHK];              //  4 KB sorted chunk
  __shared__ float4 ckbox[CHK];        //  8 KB candidate boxes
  __shared__ float carea[CHK];         //  2 KB candidate areas
  __shared__ float4 kb[MAXK];          //  kept boxes (cross-chunk / fallback)
  __shared__ float ka[MAXK];           //  kept areas
  __shared__ u64 red[256];             //  2 KB fallback reduction
  __shared__ int sh_blo, sh_run, sh_nk, sh_cc, sh_over;
  int tid = threadIdx.x;
  int lane = tid & 63;

  for (int i = tid; i < MAXK; i += 256) keepkeys[(size_t)gcls * MAXK + i] = 0ull;
  for (int i = tid; i < NB2; i += 256) hist[i] = 0u;
  if (tid == 0) { sh_nk = 0; sh_over = 0; }
  __syncthreads();

  unsigned Mraw = cnt[gcls * 16];
  bool overflow = (Mraw > (unsigned)capsel);   // p < 1e-25: full brute force below
  int M = overflow ? 0 : (int)Mraw;

  const u64* src = keybuf + (size_t)gcls * capsel;
  for (int i = tid; i < M; i += 256) {
    u64 k = src[i];
    karr[i] = k;
    atomicAdd(&hist[(unsigned)(k >> 44) & (NB2 - 1)], 1u);
  }
  __syncthreads();

  const float4* bx4 = (const float4*)(boxes + (size_t)b * N_ * 4);
  int nk = 0;                          // authoritative in wave 0 during chunk loop
  int bhi = NB2, ext = 0;

  while (ext < M && sh_nk < MAXK) {
    if (tid == 0) {
      int rem = M - ext, run = 0, bb = bhi;
      while (bb > 0) {
        unsigned h = hist[bb - 1];
        if (run + (int)h > CHK) break;
        run += (int)h; --bb;
        if (run >= 480 || run >= rem) break;
      }
      if (run == 0) sh_over = 1;   // single bin > CHK keys (never for uniform scores)
      sh_blo = bb; sh_run = run; sh_cc = 0;
    }
    __syncthreads();
    if (sh_over) break;
    int blo = sh_blo, run = sh_run;

    // compact keys with bin in [blo, bhi)
    for (int i = tid; i < M; i += 256) {
      u64 k = karr[i];
      int bin = (int)((unsigned)(k >> 44) & (NB2 - 1));
      if (bin >= blo && bin < bhi) { int p = atomicAdd(&sh_cc, 1); ck[p] = k; }
    }
    for (int i = run + tid; i < CHK; i += 256) ck[i] = 0ull;
    __syncthreads();

    // bitonic sort CHK keys descending (score desc, anchor asc via ~n packing)
    for (int kk2 = 2; kk2 <= CHK; kk2 <<= 1) {
      for (int j = kk2 >> 1; j > 0; j >>= 1) {
        if (tid < CHK / 2) {
          int i1 = 2 * tid - (tid & (j - 1));
          int i2 = i1 | j;
          u64 a = ck[i1], bb2 = ck[i2];
          bool desc = ((i1 & kk2) == 0);
          bool sw = desc ? (a < bb2) : (a > bb2);
          if (sw) { ck[i1] = bb2; ck[i2] = a; }
        }
        __syncthreads();
      }
    }

    // stage candidate boxes + areas into LDS
    for (int i = tid; i < run; i += 256) {
      float4 bxv = bx4[0xFFFFFFFFu - (unsigned)(ck[i] & 0xFFFFFFFFull)];
      ckbox[i] = bxv;
      carea[i] = area_of(bxv.x, bxv.y, bxv.z, bxv.w);
    }
    for (int i = run + tid; i < CHK; i += 256) {
      ckbox[i] = make_float4(0.f, 0.f, 0.f, 0.f);
      carea[i] = 0.f;
    }
    __syncthreads();

    // bitmask greedy on wave 0: pop lowest alive bit == next keep (exact greedy order);
    // each keep does one wave-parallel suppress (8 IOU sets -> 8 ballots)
    if (tid < 64) {
      float4 cb_[8]; float ca_[8];
#pragma unroll
      for (int s = 0; s < 8; ++s) { cb_[s] = ckbox[s * 64 + lane]; ca_[s] = carea[s * 64 + lane]; }
      u64 alive[8];
#pragma unroll
      for (int s = 0; s < 8; ++s) {
        int lo = s * 64;
        alive[s] = (run >= lo + 64) ? ~0ull
                 : (run > lo ? ((1ull << (run - lo)) - 1ull) : 0ull);
      }
      // suppress by keeps from previous chunks (rare: only when ext > 0)
      for (int j = 0; j < nk; ++j) {
        float4 sb = kb[j]; float sa = ka[j];
#pragma unroll
        for (int s = 0; s < 8; ++s)
          alive[s] &= ~__ballot(iou_gt(sb.x, sb.y, sb.z, sb.w, sa,
                                       cb_[s].x, cb_[s].y, cb_[s].z, cb_[s].w, ca_[s]));
      }
#pragma unroll 1
      for (int w = 0; w < 8; ++w) {
        while (alive[w] != 0ull && nk < MAXK) {
          int bit = __ffsll((long long)alive[w]) - 1;
          int i = w * 64 + bit;
          float4 sb = ckbox[i];        // wave-uniform broadcast reads
          float sa = carea[i];
          u64 key = ck[i];
          if (lane == 0) {
            unsigned anchor = 0xFFFFFFFFu - (unsigned)(key & 0xFFFFFFFFull);
            unsigned flat = anchor * C_ + (unsigned)c;
            keepkeys[(size_t)gcls * MAXK + nk] =
                (key & 0xFFFFFFFF00000000ull) | (u64)(0xFFFFFFFFu - flat);
            kb[nk] = sb; ka[nk] = sa;
          }
          ++nk;
#pragma unroll
          for (int s = 0; s < 8; ++s)
            alive[s] &= ~__ballot(iou_gt(sb.x, sb.y, sb.z, sb.w, sa,
                                         cb_[s].x, cb_[s].y, cb_[s].z, cb_[s].w, ca_[s]));
          // self-bit always cleared (self-IOU ~ 1 > 0.1); lower bits already processed
        }
        if (nk >= MAXK) break;
      }
      if (lane == 0) sh_nk = nk;
    }
    __syncthreads();
    ext += run;
    bhi = blo;
  }

  // ---- inline exact continuation (cold path) ----
  int nkF = sh_nk;
  if (nkF < MAXK) {
    float teff;
    if (overflow)     teff = 2.0f;
    else if (sh_over) teff = __uint_as_float(0x3F000000u | (((unsigned)bhi << 12) - 1u));
    else              teff = t0;
    const float* sbase = cls + (size_t)b * N_ * C_ + c;
    const float* bx = boxes + (size_t)b * N_ * 4;
    u64* kkp = keepkeys + (size_t)gcls * MAXK;
    int nk2 = nkF;
    while (nk2 < MAXK) {
      u64 best = 0ull;
      for (int n = tid; n < N_; n += 256) {
        float s = sbase[(size_t)n * C_];
        if (s > THR && s <= teff) {
          float y1 = bx[(size_t)n * 4 + 0], x1 = bx[(size_t)n * 4 + 1];
          float y2 = bx[(size_t)n * 4 + 2], x2 = bx[(size_t)n * 4 + 3];
          float ar = area_of(y1, x1, y2, x2);
          bool ov = false;
          for (int j = 0; j < nk2; ++j) {
            float4 kbj = kb[j];
            if (iou_gt(kbj.x, kbj.y, kbj.z, kbj.w, ka[j], y1, x1, y2, x2, ar)) { ov = true; break; }
          }
          if (!ov) {
            u64 key = ((u64)__float_as_uint(s) << 32) | (u64)(0xFFFFFFFFu - (unsigned)n);
            best = umax64(best, key);
          }
        }
      }
      red[tid] = best;
      __syncthreads();
      for (int sft = 128; sft > 0; sft >>= 1) {
        if (tid < sft) red[tid] = umax64(red[tid], red[tid + sft]);
        __syncthreads();
      }
      u64 sel = red[0];
      __syncthreads();
      if (sel == 0ull) {
        if (tid == 0) {  // exhausted before MAXK: reference quirk -> keep[anchor 0] = False
          unsigned target = 0xFFFFFFFFu - (unsigned)c;  // anchor 0 -> flat == c
          for (int j = 0; j < nk2; ++j)
            if ((unsigned)(kkp[j] & 0xFFFFFFFFull) == target) kkp[j] = 0ull;
        }
        break;
      }
      unsigned anchor = 0xFFFFFFFFu - (unsigned)(sel & 0xFFFFFFFFull);
      if (tid == 0) {
        float y1 = bx[(size_t)anchor * 4 + 0], x1 = bx[(size_t)anchor * 4 + 1];
        float y2 = bx[(size_t)anchor * 4 + 2], x2 = bx[(size_t)anchor * 4 + 3];
        kb[nk2] = make_float4(y1, x1, y2, x2);
        ka[nk2] = area_of(y1, x1, y2, x2);
        unsigned flat = anchor * C_ + (unsigned)c;
        kkp[nk2] = (sel & 0xFFFFFFFF00000000ull) | (u64)(0xFFFFFFFFu - flat);
      }
      ++nk2;
      __syncthreads();
    }
    nkF = nk2;
  }
  if (tid == 0) nk_arr[gcls] = nkF;
}

// ---------- kernel C (r7-verbatim): histogram-threshold top-100 + 512 bitonic ----------
__global__ __launch_bounds__(256) void merge_kernel(const float* __restrict__ boxes,
                                                    const u64* __restrict__ keepkeys,
                                                    const int* __restrict__ nk_arr,
                                                    float* __restrict__ out) {
  int b = blockIdx.x;
  int tid = threadIdx.x;
  int lane = tid & 63;
  int wid = tid >> 6;
  __shared__ unsigned hist[NBIN_M];
  __shared__ unsigned sfx[NBIN_M];
  __shared__ unsigned wsum[4];
  __shared__ u64 mk[512];
  __shared__ u64 selk[MAXK];
  __shared__ int sh_thr;
  __shared__ unsigned sh_cc;
  const u64* kk = keepkeys + (size_t)b * C_ * MAXK;
  const int TOT = C_ * MAXK;           // 9000

  for (int i = tid; i < NBIN_M; i += 256) hist[i] = 0u;
  if (tid == 0) { sh_thr = -1; sh_cc = 0u; }
  __syncthreads();
  for (int i = tid; i < TOT; i += 256) {
    u64 k = kk[i];
    if (k != 0ull) atomicAdd(&hist[key2bin_m(k)], 1u);
  }
  __syncthreads();

  const int W = 5;
  int j0 = tid * W;
  unsigned psum = 0;
#pragma unroll
  for (int q = 0; q < W; ++q) {
    int bin = NBIN_M - 1 - (j0 + q);
    if (bin >= 0) psum += hist[bin];
  }
  unsigned incl = psum;
#pragma unroll
  for (int s = 1; s < 64; s <<= 1) {
    unsigned v = (unsigned)__shfl_up((int)incl, s);
    if (lane >= s) incl += v;
  }
  if (lane == 63) wsum[wid] = incl;
  __syncthreads();
  unsigned base = 0;
  for (int w2 = 0; w2 < wid; ++w2) base += wsum[w2];
  unsigned running = base + incl - psum;
  int mythr = -1;
#pragma unroll
  for (int q = 0; q < W; ++q) {
    int bin = NBIN_M - 1 - (j0 + q);
    if (bin >= 0) {
      running += hist[bin];
      sfx[bin] = running;
      if (mythr < 0 && running >= (unsigned)MAXK) mythr = bin;
    }
  }
  if (mythr >= 0) atomicMax(&sh_thr, mythr);
  __syncthreads();

  int thr = sh_thr; if (thr < 0) thr = 0;
  unsigned S = sfx[thr];

  if (S <= 512u) {
    for (int i = tid; i < TOT; i += 256) {
      u64 k = kk[i];
      if (k != 0ull && key2bin_m(k) >= thr) {
        unsigned pos = atomicAdd(&sh_cc, 1u);
        mk[pos] = k;
      }
    }
    __syncthreads();
    for (int i = (int)S + tid; i < 512; i += 256) mk[i] = 0ull;
    __syncthreads();
    for (int k2 = 2; k2 <= 512; k2 <<= 1) {
      for (int j = k2 >> 1; j > 0; j >>= 1) {
        int i1 = 2 * tid - (tid & (j - 1));
        int i2 = i1 | j;
        u64 a = mk[i1], bb2 = mk[i2];
        bool desc = ((i1 & k2) == 0);
        bool sw = desc ? (a < bb2) : (a > bb2);
        if (sw) { mk[i1] = bb2; mk[i2] = a; }
        __syncthreads();
      }
    }
    for (int r = tid; r < MAXK; r += 256) selk[r] = mk[r];
    __syncthreads();
  } else {
    // degenerate tie flood: exact serial tournament on wave 0
    if (wid == 0) {
      int c0 = lane, c1 = lane + 64;
      int len0 = (c0 < C_) ? nk_arr[b * C_ + c0] : 0;
      int len1 = (c1 < C_) ? nk_arr[b * C_ + c1] : 0;
      int h0 = 0, h1 = 0;
      auto fetchc = [&](int cc, int& h, int len) -> u64 {
        while (h < len) {
          u64 k = kk[(size_t)cc * MAXK + h];
          if (k != 0ull) return k;
          ++h;
        }
        return 0ull;
      };
      u64 cand0 = (c0 < C_) ? fetchc(c0, h0, len0) : 0ull;
      u64 cand1 = (c1 < C_) ? fetchc(c1, h1, len1) : 0ull;
      for (int r = 0; r < MAXK; ++r) {
        u64 my = umax64(cand0, cand1);
        u64 g = my;
#pragma unroll
        for (int m = 1; m < 64; m <<= 1) g = umax64(g, shfl_xor_u64(g, m));
        if (lane == 0) selk[r] = g;
        if (g != 0ull && my == g) {
          if (cand0 == g) { ++h0; cand0 = fetchc(c0, h0, len0); }
          else            { ++h1; cand1 = fetchc(c1, h1, len1); }
        }
      }
    }
    __syncthreads();
  }

  for (int r = tid; r < MAXK; r += 256) {
    u64 s = selk[r];
    float oy1, ox1, oy2, ox2, sc, lb;
    if (s != 0ull) {
      unsigned flat = 0xFFFFFFFFu - (unsigned)(s & 0xFFFFFFFFull);
      unsigned anchor = flat / C_;
      unsigned label = flat - anchor * C_;
      sc = __uint_as_float((unsigned)(s >> 32));
      const float4 bp = ((const float4*)(boxes + (size_t)b * N_ * 4))[anchor];
      oy1 = bp.x; ox1 = bp.y; oy2 = bp.z; ox2 = bp.w;
      lb = (float)label;
    } else {
      oy1 = ox1 = oy2 = ox2 = -1.0f; sc = -1.0f; lb = -1.0f;
    }
    float* bo = out + ((size_t)b * MAXK + r) * 4;
    bo[0] = oy1; bo[1] = ox1; bo[2] = oy2; bo[3] = ox2;
    out[(size_t)B_ * MAXK * 4 + b * MAXK + r] = sc;
    out[(size_t)B_ * MAXK * 4 + B_ * MAXK + b * MAXK + r] = lb;
  }
}

extern "C" void kernel_launch(void* const* d_in, const int* in_sizes, int n_in,
                              void* d_out, int out_size, void* d_ws, size_t ws_size,
                              hipStream_t stream) {
  const float* boxes = (const float*)d_in[0];   // [B,N,4]
  const float* cls = (const float*)d_in[1];     // [B,N,C]
  char* ws = (char*)d_ws;

  // capacity/threshold tiers by available workspace (all t0 >= 0.93 for BINBASE validity)
  int capsel; float t0;
  auto need_for = [](int cap) -> size_t {
    return 23040 + (size_t)NCLS * cap * 8 + 288000 + 1440;
  };
  if (ws_size >= need_for(4096))      { capsel = 4096; t0 = 0.93f;  }  // M ~ 3437 +/- 57
  else if (ws_size >= need_for(2048)) { capsel = 2048; t0 = 0.962f; }  // M ~ 1866 +/- 42
  else                                { capsel = 1024; t0 = 0.985f; }  // M ~  737 +/- 27

  unsigned* cnt = (unsigned*)ws;                      // 360 counters, 64B padded
  u64* keybuf = (u64*)(ws + 23040);
  size_t off = 23040 + (size_t)NCLS * capsel * 8;
  u64* keepkeys = (u64*)(ws + off);      off += 288000;
  int* nk_arr = (int*)(ws + off);

  hipMemsetAsync(cnt, 0, 23040, stream);
  select_kernel<<<B_ * NCH, 256, 0, stream>>>(cls, keybuf, cnt, capsel, t0);
  nms_kernel<<<NCLS, 256, 0, stream>>>(boxes, cls, keybuf, cnt, capsel, t0,
                                       keepkeys, nk_arr);
  merge_kernel<<<B_, 256, 0, stream>>>(boxes, keepkeys, nk_arr, (float*)d_out);
}